// Round 1
// baseline (329.150 us; speedup 1.0000x reference)
//
#include <hip/hip_runtime.h>

typedef unsigned short u16;
typedef __attribute__((ext_vector_type(4))) float f32x4;
typedef __attribute__((ext_vector_type(8))) __bf16 bf16x8;
typedef __attribute__((ext_vector_type(8))) short short8;
typedef __attribute__((ext_vector_type(4))) u16 u16x4;

__device__ __forceinline__ u16 f2bf(float f) {
    union { float f; unsigned u; } v; v.f = f;
    unsigned r = v.u + 0x7fffu + ((v.u >> 16) & 1u);
    return (u16)(r >> 16);
}

__device__ __forceinline__ f32x4 mfma16(bf16x8 a, bf16x8 b, f32x4 c) {
    return __builtin_amdgcn_mfma_f32_16x16x32_bf16(a, b, c, 0, 0, 0);
}

__device__ __forceinline__ void gload16(const u16* g, u16* lds) {
    __builtin_amdgcn_global_load_lds(
        (const __attribute__((address_space(1))) void*)g,
        (__attribute__((address_space(3))) void*)lds, 16, 0, 0);
}

// ---------------- f32 -> bf16 conversion ----------------
__global__ void cvt_bf16_kernel(const float* __restrict__ src, u16* __restrict__ dst, int n4) {
    int i = blockIdx.x * blockDim.x + threadIdx.x;
    if (i >= n4) return;
    float4 v = ((const float4*)src)[i];
    u16x4 o = { f2bf(v.x), f2bf(v.y), f2bf(v.z), f2bf(v.w) };
    *(u16x4*)&dst[i * 4] = o;
}

// ---------------- RoPE cos/sin table [2048][32] ----------------
__global__ void rope_tbl_kernel(const int* __restrict__ pos, float2* __restrict__ tbl) {
    int i = blockIdx.x * blockDim.x + threadIdx.x;   // 65536
    int s = i >> 5, p = i & 31;
    float inv = powf(10000.0f, -(float)p / 32.0f);
    float a = (float)pos[s] * inv;
    float sn, cs;
    sincosf(a, &sn, &cs);
    tbl[i] = make_float2(cs, sn);
}

// ---------------- GEMM C = A @ B^T  (m97 structure, 128x128 tile, BK=32) ------
// A: [M][1024] bf16, B: [N][1024] bf16.
// MODE 0: C[row][N] f32 output.
// MODE 1: QKV epilogue: RoPE + split into Q[bh][s][64], K[bh][s][64], VT[bh][64][s].
template<int MODE>
__global__ __launch_bounds__(256) void gemm_bt(
    const u16* __restrict__ A, const u16* __restrict__ B,
    float* __restrict__ C, int N,
    u16* __restrict__ Qt, u16* __restrict__ Ktn, u16* __restrict__ VTt,
    const float2* __restrict__ tbl)
{
    __shared__ alignas(16) u16 As[128 * 32];
    __shared__ alignas(16) u16 Bs[128 * 32];
    const int t = threadIdx.x;
    const int l = t & 63, w = t >> 6;
    const int lg = l >> 4, lc = l & 15;
    const int wr = w >> 1, wc = w & 1;
    const int brow = blockIdx.y * 128, bcol = blockIdx.x * 128;
    const int sr = w * 16 + (l >> 2), sc = (l & 3) * 8;
    const u16* ga = A + (size_t)(brow + sr) * 1024 + sc;
    const u16* gb = B + (size_t)(bcol + sr) * 1024 + sc;
    u16* la = &As[w * 512];
    u16* lb = &Bs[w * 512];
    f32x4 acc[4][4] = {};

    for (int kt = 0; kt < 1024; kt += 32) {
        __syncthreads();
        gload16(ga + kt, la);
        gload16(ga + 64 * 1024 + kt, la + 2048);
        gload16(gb + kt, lb);
        gload16(gb + 64 * 1024 + kt, lb + 2048);
        __syncthreads();
        bf16x8 af[4], bfr[4];
#pragma unroll
        for (int i = 0; i < 4; ++i)
            af[i] = *(const bf16x8*)&As[(wr * 64 + i * 16 + lc) * 32 + lg * 8];
#pragma unroll
        for (int j = 0; j < 4; ++j)
            bfr[j] = *(const bf16x8*)&Bs[(wc * 64 + j * 16 + lc) * 32 + lg * 8];
#pragma unroll
        for (int i = 0; i < 4; ++i)
#pragma unroll
            for (int j = 0; j < 4; ++j)
                acc[i][j] = mfma16(af[i], bfr[j], acc[i][j]);
    }

    if (MODE == 0) {
#pragma unroll
        for (int i = 0; i < 4; ++i) {
            int row = brow + wr * 64 + i * 16 + lg * 4;
#pragma unroll
            for (int j = 0; j < 4; ++j) {
                int col = bcol + wc * 64 + j * 16 + lc;
#pragma unroll
                for (int jj = 0; jj < 4; ++jj)
                    C[(size_t)(row + jj) * N + col] = acc[i][j][jj];
            }
        }
    } else {
        const int b = brow >> 11;
#pragma unroll
        for (int i = 0; i < 4; ++i) {
            int s0 = (brow & 2047) + wr * 64 + i * 16 + lg * 4;
#pragma unroll
            for (int j = 0; j < 4; ++j) {
                int e0 = bcol + wc * 64 + j * 16;     // wave-uniform
                int region = e0 >> 10;                // 0=q 1=k 2=v
                int er = e0 & 1023;
                int h = er >> 6;                      // wave-uniform
                int d = (er & 63) + lc;               // per-lane
                size_t bh = (size_t)(b * 16 + h);
                if (region <= 1) {
                    int p = d >> 1;
                    float sgn = (d & 1) ? 1.0f : -1.0f;   // even: -sin, odd: +sin
                    u16* dst = (region == 0) ? Qt : Ktn;
                    float mul = (region == 0) ? 0.125f : 1.0f;
#pragma unroll
                    for (int jj = 0; jj < 4; ++jj) {
                        float v = acc[i][j][jj];
                        float pr = __shfl_xor(v, 1);
                        float2 cs = tbl[(size_t)(s0 + jj) * 32 + p];
                        float o = (v * cs.x + pr * cs.y * sgn) * mul;
                        dst[(bh * 2048 + s0 + jj) * 64 + d] = f2bf(o);
                    }
                } else {
                    u16x4 pk;
#pragma unroll
                    for (int jj = 0; jj < 4; ++jj) pk[jj] = f2bf(acc[i][j][jj]);
                    *(u16x4*)&VTt[(bh * 64 + d) * 2048 + s0] = pk;
                }
            }
        }
    }
}

// ---------------- causal flash attention ----------------
// grid: 2048 blocks = 32 q-tiles (heavy first) x 64 bh. 4 waves x 16 q-rows, KVBLK=64.
__global__ __launch_bounds__(256) void attn_kernel(
    const u16* __restrict__ Qt, const u16* __restrict__ Kt,
    const u16* __restrict__ VTt, u16* __restrict__ O)
{
    __shared__ alignas(16) u16 Kl[64 * 72];
    __shared__ alignas(16) u16 Vl[64 * 72];
    __shared__ alignas(16) u16 Pl[4 * 16 * 72];
    const int bid = blockIdx.x;
    const int qt = 31 - (bid >> 6);      // heavy q-tiles dispatched first
    const int bh = bid & 63;
    const int t = threadIdx.x, l = t & 63, w = t >> 6;
    const int lg = l >> 4, lc = l & 15;
    const int qw0 = qt * 64 + w * 16;

    const size_t qoff = ((size_t)bh * 2048 + qw0 + lc) * 64 + lg * 8;
    bf16x8 qf[2];
    qf[0] = *(const bf16x8*)&Qt[qoff];
    qf[1] = *(const bf16x8*)&Qt[qoff + 32];

    f32x4 aco[4] = {};
    float m[4], ls[4];
#pragma unroll
    for (int jj = 0; jj < 4; ++jj) { m[jj] = -1e30f; ls[jj] = 0.0f; }

    const int r = t >> 2, cseg = (t & 3) * 16;
    const u16* gK = Kt + (size_t)bh * 2048 * 64;
    const u16* gV = VTt + (size_t)bh * 64 * 2048;

    for (int kt = 0; kt <= qt; ++kt) {
        const int kv0 = kt * 64;
        __syncthreads();
        // stage K tile [kv][64d] and V^T tile [d][64kv] into +8-padded LDS
        *(short8*)&Kl[r * 72 + cseg]     = *(const short8*)&gK[(size_t)(kv0 + r) * 64 + cseg];
        *(short8*)&Kl[r * 72 + cseg + 8] = *(const short8*)&gK[(size_t)(kv0 + r) * 64 + cseg + 8];
        *(short8*)&Vl[r * 72 + cseg]     = *(const short8*)&gV[(size_t)r * 2048 + kv0 + cseg];
        *(short8*)&Vl[r * 72 + cseg + 8] = *(const short8*)&gV[(size_t)r * 2048 + kv0 + cseg + 8];
        __syncthreads();

        // S = Q K^T (q pre-scaled by 1/8)
        f32x4 sc[4];
#pragma unroll
        for (int nb = 0; nb < 4; ++nb) {
            sc[nb] = (f32x4){0.f, 0.f, 0.f, 0.f};
#pragma unroll
            for (int fk = 0; fk < 2; ++fk) {
                bf16x8 kb = *(const bf16x8*)&Kl[(nb * 16 + lc) * 72 + fk * 32 + lg * 8];
                sc[nb] = mfma16(qf[fk], kb, sc[nb]);
            }
        }

        // causal mask + per-row tile max
        float mt[4] = { -1e30f, -1e30f, -1e30f, -1e30f };
#pragma unroll
        for (int nb = 0; nb < 4; ++nb) {
            int kvi = kv0 + nb * 16 + lc;
#pragma unroll
            for (int jj = 0; jj < 4; ++jj) {
                float sv = sc[nb][jj];
                int qi = qw0 + lg * 4 + jj;
                sv = (kvi > qi) ? -1e30f : sv;
                sc[nb][jj] = sv;
                mt[jj] = fmaxf(mt[jj], sv);
            }
        }
#pragma unroll
        for (int jj = 0; jj < 4; ++jj) {
            mt[jj] = fmaxf(mt[jj], __shfl_xor(mt[jj], 1));
            mt[jj] = fmaxf(mt[jj], __shfl_xor(mt[jj], 2));
            mt[jj] = fmaxf(mt[jj], __shfl_xor(mt[jj], 4));
            mt[jj] = fmaxf(mt[jj], __shfl_xor(mt[jj], 8));
        }
        // online softmax update
        float rs[4] = { 0.f, 0.f, 0.f, 0.f };
#pragma unroll
        for (int jj = 0; jj < 4; ++jj) {
            float mn = fmaxf(m[jj], mt[jj]);
            float scal = __expf(m[jj] - mn);
            m[jj] = mn;
            ls[jj] *= scal;
#pragma unroll
            for (int nb = 0; nb < 4; ++nb) aco[nb][jj] *= scal;
        }
#pragma unroll
        for (int nb = 0; nb < 4; ++nb)
#pragma unroll
            for (int jj = 0; jj < 4; ++jj) {
                float pv = __expf(sc[nb][jj] - m[jj]);
                sc[nb][jj] = pv;
                rs[jj] += pv;
            }
#pragma unroll
        for (int jj = 0; jj < 4; ++jj) {
            rs[jj] += __shfl_xor(rs[jj], 1);
            rs[jj] += __shfl_xor(rs[jj], 2);
            rs[jj] += __shfl_xor(rs[jj], 4);
            rs[jj] += __shfl_xor(rs[jj], 8);
            ls[jj] += rs[jj];
        }

        // P -> per-wave LDS (transpose to A-fragment layout)
#pragma unroll
        for (int nb = 0; nb < 4; ++nb)
#pragma unroll
            for (int jj = 0; jj < 4; ++jj)
                Pl[w * 1152 + (lg * 4 + jj) * 72 + nb * 16 + lc] = f2bf(sc[nb][jj]);
        __syncthreads();

        bf16x8 pa[2];
        pa[0] = *(const bf16x8*)&Pl[w * 1152 + lc * 72 + lg * 8];
        pa[1] = *(const bf16x8*)&Pl[w * 1152 + lc * 72 + lg * 8 + 32];
#pragma unroll
        for (int nb = 0; nb < 4; ++nb)
#pragma unroll
            for (int fk = 0; fk < 2; ++fk) {
                bf16x8 vb = *(const bf16x8*)&Vl[(nb * 16 + lc) * 72 + fk * 32 + lg * 8];
                aco[nb] = mfma16(pa[fk], vb, aco[nb]);
            }
    }

    const int b = bh >> 4, h = bh & 15;
#pragma unroll
    for (int jj = 0; jj < 4; ++jj) {
        float inv = 1.0f / ls[jj];
        size_t row = (size_t)b * 2048 + qw0 + lg * 4 + jj;
#pragma unroll
        for (int nb = 0; nb < 4; ++nb)
            O[row * 1024 + h * 64 + nb * 16 + lc] = f2bf(aco[nb][jj] * inv);
    }
}

// ---------------- launch ----------------
extern "C" void kernel_launch(void* const* d_in, const int* in_sizes, int n_in,
                              void* d_out, int out_size, void* d_ws, size_t ws_size,
                              hipStream_t stream) {
    const float* x    = (const float*)d_in[0];
    const int*   pos  = (const int*)d_in[1];
    const float* wqkv = (const float*)d_in[2];
    const float* wout = (const float*)d_in[3];
    float* out = (float*)d_out;
    char* ws = (char*)d_ws;

    // workspace layout (bytes)
    u16*    x_bf    = (u16*)(ws);                    // 16,777,216
    u16*    wqkv_bf = (u16*)(ws + 16777216);         //  6,291,456
    u16*    wout_bf = (u16*)(ws + 23068672);         //  2,097,152
    float2* tbl     = (float2*)(ws + 25165824);      //    524,288
    u16*    Qt      = (u16*)(ws + 25690112);         // 16,777,216
    u16*    Kt      = (u16*)(ws + 42467328);         // 16,777,216
    u16*    VTt     = (u16*)(ws + 59244544);         // 16,777,216
    u16*    O       = (u16*)(ws + 76021760);         // 16,777,216 -> end 92,798,976
    if (ws_size < 92798976u) return;  // loud failure (output stays poisoned)

    cvt_bf16_kernel<<<8192, 256, 0, stream>>>(x, x_bf, 2097152);
    cvt_bf16_kernel<<<3072, 256, 0, stream>>>(wqkv, wqkv_bf, 786432);
    cvt_bf16_kernel<<<1024, 256, 0, stream>>>(wout, wout_bf, 262144);
    rope_tbl_kernel<<<256, 256, 0, stream>>>(pos, tbl);

    dim3 g1(24, 64);   // N=3072/128, M=8192/128
    gemm_bt<1><<<g1, 256, 0, stream>>>(x_bf, wqkv_bf, nullptr, 0, Qt, Kt, VTt, tbl);

    attn_kernel<<<2048, 256, 0, stream>>>(Qt, Kt, VTt, O);

    dim3 g2(8, 64);    // N=1024/128
    gemm_bt<0><<<g2, 256, 0, stream>>>(O, wout_bf, out, 1024, nullptr, nullptr, nullptr, nullptr);
}

// Round 2
// 309.407 us; speedup vs baseline: 1.0638x; 1.0638x over previous
//
#include <hip/hip_runtime.h>

typedef unsigned short u16;
typedef __attribute__((ext_vector_type(4))) float f32x4;
typedef __attribute__((ext_vector_type(8))) __bf16 bf16x8;
typedef __attribute__((ext_vector_type(4))) __bf16 bf16x4;
typedef __attribute__((ext_vector_type(8))) short short8;
typedef __attribute__((ext_vector_type(4))) u16 u16x4;

__device__ __forceinline__ u16 f2bf(float f) {
    union { float f; unsigned u; } v; v.f = f;
    unsigned r = v.u + 0x7fffu + ((v.u >> 16) & 1u);
    return (u16)(r >> 16);
}

__device__ __forceinline__ f32x4 mfma16(bf16x8 a, bf16x8 b, f32x4 c) {
    return __builtin_amdgcn_mfma_f32_16x16x32_bf16(a, b, c, 0, 0, 0);
}

__device__ __forceinline__ void gload16(const u16* g, u16* lds) {
    __builtin_amdgcn_global_load_lds(
        (const __attribute__((address_space(1))) void*)g,
        (__attribute__((address_space(3))) void*)lds, 16, 0, 0);
}

// ---------------- f32 -> bf16 conversion ----------------
__global__ void cvt_bf16_kernel(const float* __restrict__ src, u16* __restrict__ dst, int n4) {
    int i = blockIdx.x * blockDim.x + threadIdx.x;
    if (i >= n4) return;
    float4 v = ((const float4*)src)[i];
    u16x4 o = { f2bf(v.x), f2bf(v.y), f2bf(v.z), f2bf(v.w) };
    *(u16x4*)&dst[i * 4] = o;
}

// ---------------- RoPE cos/sin table [2048][32] ----------------
__global__ void rope_tbl_kernel(const int* __restrict__ pos, float2* __restrict__ tbl) {
    int i = blockIdx.x * blockDim.x + threadIdx.x;   // 65536
    int s = i >> 5, p = i & 31;
    float inv = powf(10000.0f, -(float)p / 32.0f);
    float a = (float)pos[s] * inv;
    float sn, cs;
    sincosf(a, &sn, &cs);
    tbl[i] = make_float2(cs, sn);
}

// ---------------- GEMM C = A @ B^T  (m97 structure, 128x128 tile, BK=32) ------
// MODE 0: C[row][N] f32 output.
// MODE 1: QKV epilogue: RoPE + split into Q[bh][s][64] (pre-scaled by 1/8*log2e),
//         K[bh][s][64], VT[bh][64][s].
template<int MODE>
__global__ __launch_bounds__(256) void gemm_bt(
    const u16* __restrict__ A, const u16* __restrict__ B,
    float* __restrict__ C, int N,
    u16* __restrict__ Qt, u16* __restrict__ Ktn, u16* __restrict__ VTt,
    const float2* __restrict__ tbl)
{
    __shared__ alignas(16) u16 As[128 * 32];
    __shared__ alignas(16) u16 Bs[128 * 32];
    const int t = threadIdx.x;
    const int l = t & 63, w = t >> 6;
    const int lg = l >> 4, lc = l & 15;
    const int wr = w >> 1, wc = w & 1;
    const int brow = blockIdx.y * 128, bcol = blockIdx.x * 128;
    const int sr = w * 16 + (l >> 2), sc = (l & 3) * 8;
    const u16* ga = A + (size_t)(brow + sr) * 1024 + sc;
    const u16* gb = B + (size_t)(bcol + sr) * 1024 + sc;
    u16* la = &As[w * 512];
    u16* lb = &Bs[w * 512];
    f32x4 acc[4][4] = {};

    for (int kt = 0; kt < 1024; kt += 32) {
        __syncthreads();
        gload16(ga + kt, la);
        gload16(ga + 64 * 1024 + kt, la + 2048);
        gload16(gb + kt, lb);
        gload16(gb + 64 * 1024 + kt, lb + 2048);
        __syncthreads();
        bf16x8 af[4], bfr[4];
#pragma unroll
        for (int i = 0; i < 4; ++i)
            af[i] = *(const bf16x8*)&As[(wr * 64 + i * 16 + lc) * 32 + lg * 8];
#pragma unroll
        for (int j = 0; j < 4; ++j)
            bfr[j] = *(const bf16x8*)&Bs[(wc * 64 + j * 16 + lc) * 32 + lg * 8];
#pragma unroll
        for (int i = 0; i < 4; ++i)
#pragma unroll
            for (int j = 0; j < 4; ++j)
                acc[i][j] = mfma16(af[i], bfr[j], acc[i][j]);
    }

    if (MODE == 0) {
#pragma unroll
        for (int i = 0; i < 4; ++i) {
            int row = brow + wr * 64 + i * 16 + lg * 4;
#pragma unroll
            for (int j = 0; j < 4; ++j) {
                int col = bcol + wc * 64 + j * 16 + lc;
#pragma unroll
                for (int jj = 0; jj < 4; ++jj)
                    C[(size_t)(row + jj) * N + col] = acc[i][j][jj];
            }
        }
    } else {
        const int b = brow >> 11;
#pragma unroll
        for (int i = 0; i < 4; ++i) {
            int s0 = (brow & 2047) + wr * 64 + i * 16 + lg * 4;
#pragma unroll
            for (int j = 0; j < 4; ++j) {
                int e0 = bcol + wc * 64 + j * 16;     // wave-uniform
                int region = e0 >> 10;                // 0=q 1=k 2=v
                int er = e0 & 1023;
                int h = er >> 6;                      // wave-uniform
                int d = (er & 63) + lc;               // per-lane
                size_t bh = (size_t)(b * 16 + h);
                if (region <= 1) {
                    int p = d >> 1;
                    float sgn = (d & 1) ? 1.0f : -1.0f;   // even: -sin, odd: +sin
                    u16* dst = (region == 0) ? Qt : Ktn;
                    // Q pre-scaled by (1/sqrt(64)) * log2(e) so attention works in exp2 domain
                    float mul = (region == 0) ? 0.18033688011112043f : 1.0f;
#pragma unroll
                    for (int jj = 0; jj < 4; ++jj) {
                        float v = acc[i][j][jj];
                        float pr = __shfl_xor(v, 1);
                        float2 cs = tbl[(size_t)(s0 + jj) * 32 + p];
                        float o = (v * cs.x + pr * cs.y * sgn) * mul;
                        dst[(bh * 2048 + s0 + jj) * 64 + d] = f2bf(o);
                    }
                } else {
                    u16x4 pk;
#pragma unroll
                    for (int jj = 0; jj < 4; ++jj) pk[jj] = f2bf(acc[i][j][jj]);
                    *(u16x4*)&VTt[(bh * 64 + d) * 2048 + s0] = pk;
                }
            }
        }
    }
}

// ---------------- causal flash attention (swapped-operand, P stays in regs) ---
// grid: 1024 blocks = 16 q-tiles (heavy first) x 64 bh.
// Block: 128 q rows; 4 waves x 32 q (2 fragments of 16). KVBLK=64.
// S^T = mfma(K_frag, Q_frag): lane owns q = base+lc, k = kv0 + nb*16 + lg*4 + jj.
// PV: O^T = mfma(V^T_frag(permuted cols), P_frag(from own regs)) - no shuffles.
__global__ __launch_bounds__(256) void attn_kernel(
    const u16* __restrict__ Qt, const u16* __restrict__ Kt,
    const u16* __restrict__ VTt, u16* __restrict__ O)
{
    __shared__ alignas(16) u16 Kl[64 * 72];
    __shared__ alignas(16) u16 Vl[64 * 72];
    const int bid = blockIdx.x;
    const int qt = 15 - (bid >> 6);      // heavy q-tiles dispatched first
    const int bh = bid & 63;
    const int t = threadIdx.x, l = t & 63, w = t >> 6;
    const int lg = l >> 4, lc = l & 15;
    const int qb0 = qt * 128 + w * 32;   // frag f covers q in [qb0+16f, qb0+16f+15]

    bf16x8 qf[2][2];
#pragma unroll
    for (int f = 0; f < 2; ++f)
#pragma unroll
        for (int fk = 0; fk < 2; ++fk)
            qf[f][fk] = *(const bf16x8*)&Qt[((size_t)bh * 2048 + qb0 + 16 * f + lc) * 64 + fk * 32 + lg * 8];

    f32x4 aco[2][4] = {};
    float m[2] = { -1e30f, -1e30f }, ls[2] = { 0.f, 0.f };
    const int ntiles = 2 * qt + 2;

    // staging: thread owns one 32B quarter-row of K tile and of V^T tile
    const int r = t >> 2, cg = t & 3;
    const u16* gkp = Kt + (size_t)bh * 131072 + r * 64 + cg * 16;
    const u16* gvp = VTt + (size_t)bh * 131072 + (size_t)r * 2048 + cg * 16;
    u16* wk = &Kl[r * 72 + cg * 16];
    u16* wv = &Vl[r * 72 + cg * 16];

    short8 rk0 = *(const short8*)(gkp);
    short8 rk1 = *(const short8*)(gkp + 8);
    short8 rv0 = *(const short8*)(gvp);
    short8 rv1 = *(const short8*)(gvp + 8);

    for (int kt = 0; kt < ntiles; ++kt) {
        const int kv0 = kt * 64;
        __syncthreads();                  // readers of previous tile done
        *(short8*)wk = rk0; *(short8*)(wk + 8) = rk1;
        *(short8*)wv = rv0; *(short8*)(wv + 8) = rv1;
        if (kt + 1 < ntiles) {            // T14: issue next-tile loads under compute
            const int nx = kv0 + 64;
            rk0 = *(const short8*)(gkp + (size_t)nx * 64);
            rk1 = *(const short8*)(gkp + (size_t)nx * 64 + 8);
            rv0 = *(const short8*)(gvp + nx);
            rv1 = *(const short8*)(gvp + nx + 8);
        }
        __syncthreads();                  // LDS tile visible

        const int act0 = (kv0 <= qb0 + 15);
        const int act1 = (kv0 <= qb0 + 31);

        // S^T = K Q^T
        f32x4 sc[2][4];
        const f32x4 zf = { 0.f, 0.f, 0.f, 0.f };
#pragma unroll
        for (int nb = 0; nb < 4; ++nb) {
            bf16x8 kb0 = *(const bf16x8*)&Kl[(nb * 16 + lc) * 72 + lg * 8];
            bf16x8 kb1 = *(const bf16x8*)&Kl[(nb * 16 + lc) * 72 + 32 + lg * 8];
            if (act0) {
                sc[0][nb] = mfma16(kb0, qf[0][0], zf);
                sc[0][nb] = mfma16(kb1, qf[0][1], sc[0][nb]);
            }
            if (act1) {
                sc[1][nb] = mfma16(kb0, qf[1][0], zf);
                sc[1][nb] = mfma16(kb1, qf[1][1], sc[1][nb]);
            }
        }

        // mask + per-q (in-lane) max
        float pm[2] = { -1e38f, -1e38f };
#pragma unroll
        for (int f = 0; f < 2; ++f) {
            const int act = f ? act1 : act0;
            if (!act) continue;
            const int qq = qb0 + 16 * f + lc;
            if (kv0 + 63 > qb0 + 16 * f) {
#pragma unroll
                for (int nb = 0; nb < 4; ++nb)
#pragma unroll
                    for (int jj = 0; jj < 4; ++jj) {
                        int kk = kv0 + nb * 16 + lg * 4 + jj;
                        if (kk > qq) sc[f][nb][jj] = -1e38f;
                    }
            }
            float a0 = fmaxf(fmaxf(sc[f][0][0], sc[f][0][1]), fmaxf(sc[f][0][2], sc[f][0][3]));
            float a1 = fmaxf(fmaxf(sc[f][1][0], sc[f][1][1]), fmaxf(sc[f][1][2], sc[f][1][3]));
            float a2 = fmaxf(fmaxf(sc[f][2][0], sc[f][2][1]), fmaxf(sc[f][2][2], sc[f][2][3]));
            float a3 = fmaxf(fmaxf(sc[f][3][0], sc[f][3][1]), fmaxf(sc[f][3][2], sc[f][3][3]));
            float a = fmaxf(fmaxf(a0, a1), fmaxf(a2, a3));
            a = fmaxf(a, __shfl_xor(a, 16));
            a = fmaxf(a, __shfl_xor(a, 32));
            pm[f] = a;
        }

        // defer-max (T13): rescale only when some lane's tile-max exceeds m+THR
        int need = ((act0 && pm[0] > m[0] + 11.0f) || (act1 && pm[1] > m[1] + 11.0f));
        if (__any(need)) {
#pragma unroll
            for (int f = 0; f < 2; ++f) {
                float mn = fmaxf(m[f], pm[f]);
                float scal = exp2f(m[f] - mn);
                m[f] = mn;
                ls[f] *= scal;
#pragma unroll
                for (int nb = 0; nb < 4; ++nb) aco[f][nb] *= scal;
            }
        }

        // P = exp2(S - m), partial row-sum stays per-lane, pack PV B-frags from own regs
        bf16x8 pB[2][2];
#pragma unroll
        for (int f = 0; f < 2; ++f) {
            const int act = f ? act1 : act0;
            if (!act) continue;
            float lsf = 0.f;
#pragma unroll
            for (int nb = 0; nb < 4; ++nb)
#pragma unroll
                for (int jj = 0; jj < 4; ++jj) {
                    float p = exp2f(sc[f][nb][jj] - m[f]);
                    sc[f][nb][jj] = p;
                    lsf += p;
                }
            ls[f] += lsf;
#pragma unroll
            for (int fk = 0; fk < 2; ++fk) {
                bf16x8 pb;
#pragma unroll
                for (int e = 0; e < 4; ++e) {
                    pb[e]     = (__bf16)sc[f][2 * fk][e];
                    pb[e + 4] = (__bf16)sc[f][2 * fk + 1][e];
                }
                pB[f][fk] = pb;
            }
        }

        // O^T += V^T P^T ; V^T A-frag reads the column order matching P's k-order:
        // internal word (lg,e) <-> kv = 32fk + 16*(e>>2) + 4lg + (e&3)
#pragma unroll
        for (int nb = 0; nb < 4; ++nb) {
#pragma unroll
            for (int fk = 0; fk < 2; ++fk) {
                bf16x4 vlo = *(const bf16x4*)&Vl[(nb * 16 + lc) * 72 + fk * 32 + lg * 4];
                bf16x4 vhi = *(const bf16x4*)&Vl[(nb * 16 + lc) * 72 + fk * 32 + 16 + lg * 4];
                bf16x8 va = __builtin_shufflevector(vlo, vhi, 0, 1, 2, 3, 4, 5, 6, 7);
                if (act0) aco[0][nb] = mfma16(va, pB[0][fk], aco[0][nb]);
                if (act1) aco[1][nb] = mfma16(va, pB[1][fk], aco[1][nb]);
            }
        }
    }

    // epilogue: finish row-sum across the 4-lane group, normalize, store
    const int b = bh >> 4, h = bh & 15;
#pragma unroll
    for (int f = 0; f < 2; ++f) {
        float s = ls[f];
        s += __shfl_xor(s, 16);
        s += __shfl_xor(s, 32);
        float rinv = 1.0f / s;
        size_t row = (size_t)b * 2048 + qb0 + 16 * f + lc;
#pragma unroll
        for (int nb = 0; nb < 4; ++nb) {
            u16x4 pk;
#pragma unroll
            for (int jj = 0; jj < 4; ++jj) pk[jj] = f2bf(aco[f][nb][jj] * rinv);
            *(u16x4*)&O[row * 1024 + h * 64 + nb * 16 + lg * 4] = pk;
        }
    }
}

// ---------------- launch ----------------
extern "C" void kernel_launch(void* const* d_in, const int* in_sizes, int n_in,
                              void* d_out, int out_size, void* d_ws, size_t ws_size,
                              hipStream_t stream) {
    const float* x    = (const float*)d_in[0];
    const int*   pos  = (const int*)d_in[1];
    const float* wqkv = (const float*)d_in[2];
    const float* wout = (const float*)d_in[3];
    float* out = (float*)d_out;
    char* ws = (char*)d_ws;

    // workspace layout (bytes)
    u16*    x_bf    = (u16*)(ws);                    // 16,777,216
    u16*    wqkv_bf = (u16*)(ws + 16777216);         //  6,291,456
    u16*    wout_bf = (u16*)(ws + 23068672);         //  2,097,152
    float2* tbl     = (float2*)(ws + 25165824);      //    524,288
    u16*    Qt      = (u16*)(ws + 25690112);         // 16,777,216
    u16*    Kt      = (u16*)(ws + 42467328);         // 16,777,216
    u16*    VTt     = (u16*)(ws + 59244544);         // 16,777,216
    u16*    O       = (u16*)(ws + 76021760);         // 16,777,216 -> end 92,798,976
    if (ws_size < 92798976u) return;  // loud failure (output stays poisoned)

    cvt_bf16_kernel<<<8192, 256, 0, stream>>>(x, x_bf, 2097152);
    cvt_bf16_kernel<<<3072, 256, 0, stream>>>(wqkv, wqkv_bf, 786432);
    cvt_bf16_kernel<<<1024, 256, 0, stream>>>(wout, wout_bf, 262144);
    rope_tbl_kernel<<<256, 256, 0, stream>>>(pos, tbl);

    dim3 g1(24, 64);   // N=3072/128, M=8192/128
    gemm_bt<1><<<g1, 256, 0, stream>>>(x_bf, wqkv_bf, nullptr, 0, Qt, Kt, VTt, tbl);

    attn_kernel<<<1024, 256, 0, stream>>>(Qt, Kt, VTt, O);

    dim3 g2(8, 64);    // N=1024/128
    gemm_bt<0><<<g2, 256, 0, stream>>>(O, wout_bf, out, 1024, nullptr, nullptr, nullptr, nullptr);
}